// Round 1
// baseline (859.536 us; speedup 1.0000x reference)
//
#include <hip/hip_runtime.h>

// Lovasz-Softmax without sorting:
//  - ties in the error value don't change the loss (telescoping of the
//    jaccard-difference dot product within equal-error groups)
//  - jaccard is monotone along the sorted order (TV == 1), so binning errors
//    to NB bins and using bin midpoints has error <= 0.5/NB per class.
// => histogram (count, fg-count) per class per bin, then a descending scan.

constexpr int NCLS = 6;
constexpr int HW   = 512 * 512;
constexpr int NPIX = 8 * HW;
constexpr int NB   = 16384;      // bin width 1/16384 -> loss error ~3e-5

__global__ __launch_bounds__(256) void lovasz_hist(
    const float* __restrict__ logits, const int* __restrict__ labels,
    unsigned* __restrict__ hist, unsigned* __restrict__ fgh) {
  int tid = blockIdx.x * blockDim.x + threadIdx.x;   // 0 .. NPIX/4-1
  int n4  = tid << 2;                                // 4 consecutive pixels
  if (n4 >= NPIX) return;
  int b  = n4 >> 18;                                 // / HW
  int hw = n4 & (HW - 1);

  int4 lab4 = *reinterpret_cast<const int4*>(labels + n4);
  int labs[4] = {lab4.x, lab4.y, lab4.z, lab4.w};
  if ((lab4.x | lab4.y | lab4.z | lab4.w) == 0) return;  // all ignored

  float xx[NCLS][4];
  size_t base = ((size_t)b * NCLS) << 18;
#pragma unroll
  for (int c = 0; c < NCLS; ++c) {
    float4 v = *reinterpret_cast<const float4*>(logits + base + ((size_t)c << 18) + hw);
    xx[c][0] = v.x; xx[c][1] = v.y; xx[c][2] = v.z; xx[c][3] = v.w;
  }

#pragma unroll
  for (int j = 0; j < 4; ++j) {
    int lab = labs[j];
    if (lab == 0) continue;      // IGNORE_INDEX: contributes exactly 0
    float m = xx[0][j];
#pragma unroll
    for (int c = 1; c < NCLS; ++c) m = fmaxf(m, xx[c][j]);
    float e[NCLS];
    float s = 0.f;
#pragma unroll
    for (int c = 0; c < NCLS; ++c) { e[c] = __expf(xx[c][j] - m); s += e[c]; }
    float inv = 1.0f / s;
#pragma unroll
    for (int c = 0; c < NCLS; ++c) {
      float p   = e[c] * inv;
      float err = (c == lab) ? 1.0f - p : p;      // |fg - p|
      int bin = (int)(err * (float)NB);
      bin = bin < 0 ? 0 : (bin > NB - 1 ? NB - 1 : bin);
      atomicAdd(&hist[c * NB + bin], 1u);
      if (c == lab) atomicAdd(&fgh[c * NB + bin], 1u);
    }
  }
}

// One block per class: descending-bin scan computing
//   sum over bins: e_mid * (jac(n+dn, f+df) - jac(n, f))
// jac(n,f) = 1 - (g - f)/(g + n - f); for present classes union >= g > 0.
__global__ __launch_bounds__(256) void lovasz_scan(
    const unsigned* __restrict__ hist, const unsigned* __restrict__ fgh,
    float* __restrict__ res) {
  const int c = blockIdx.x;
  const unsigned* h = hist + c * NB;
  const unsigned* g = fgh  + c * NB;
  const int t = threadIdx.x;                 // 256 threads
  const int K = NB / 256;                    // 64 bins per thread
  const int hi = NB - 1 - t * K;             // this thread's chunk: hi, hi-1, ...

  unsigned dn = 0, df = 0;
  for (int i = 0; i < K; ++i) { dn += h[hi - i]; df += g[hi - i]; }

  __shared__ unsigned sn[256], sf[256];
  sn[t] = dn; sf[t] = df;
  __syncthreads();
  // Hillis-Steele inclusive scan over thread order (== descending bin order)
  for (int off = 1; off < 256; off <<= 1) {
    unsigned an = (t >= off) ? sn[t - off] : 0u;
    unsigned af = (t >= off) ? sf[t - off] : 0u;
    __syncthreads();
    sn[t] += an; sf[t] += af;
    __syncthreads();
  }
  const unsigned total_f = sf[255];          // gts
  const unsigned n0 = sn[t] - dn;            // exclusive prefix (elems with larger e)
  const unsigned f0 = sf[t] - df;

  double contrib = 0.0;
  if (total_f > 0) {
    const double gts = (double)total_f;
    unsigned n = n0, f = f0;
    for (int i = 0; i < K; ++i) {
      int bidx = hi - i;
      unsigned dnb = h[bidx];
      if (!dnb) continue;
      unsigned dfb = g[bidx];
      double ub = gts + (double)n - (double)f;         // > 0 since gts > 0
      double jb = 1.0 - (gts - (double)f) / ub;
      n += dnb; f += dfb;
      double ua = gts + (double)n - (double)f;
      double ja = 1.0 - (gts - (double)f) / ua;
      double e  = ((double)bidx + 0.5) * (1.0 / (double)NB);
      contrib += e * (ja - jb);
    }
  }

  __shared__ double sd[256];
  sd[t] = contrib;
  __syncthreads();
  for (int off = 128; off > 0; off >>= 1) {
    if (t < off) sd[t] += sd[t + off];
    __syncthreads();
  }
  if (t == 0) {
    res[c]        = (total_f > 0) ? (float)sd[0] : 0.0f;
    res[NCLS + c] = (total_f > 0) ? 1.0f : 0.0f;
  }
}

__global__ void lovasz_final(const float* __restrict__ res, float* __restrict__ out) {
  float s = 0.f, np = 0.f;
  for (int c = 0; c < NCLS; ++c) { s += res[c]; np += res[NCLS + c]; }
  out[0] = s / fmaxf(np, 1.0f);
}

extern "C" void kernel_launch(void* const* d_in, const int* in_sizes, int n_in,
                              void* d_out, int out_size, void* d_ws, size_t ws_size,
                              hipStream_t stream) {
  const float* logits = (const float*)d_in[0];
  const int*   labels = (const int*)d_in[1];

  unsigned* hist = (unsigned*)d_ws;
  unsigned* fgh  = hist + (size_t)NCLS * NB;
  float*    res  = (float*)(fgh + (size_t)NCLS * NB);

  size_t clear_bytes = 2ull * NCLS * NB * sizeof(unsigned) + 2ull * NCLS * sizeof(float);
  hipMemsetAsync(d_ws, 0, clear_bytes, stream);

  lovasz_hist<<<NPIX / 4 / 256, 256, 0, stream>>>(logits, labels, hist, fgh);
  lovasz_scan<<<NCLS, 256, 0, stream>>>(hist, fgh, res);
  lovasz_final<<<1, 1, 0, stream>>>(res, (float*)d_out);
}

// Round 2
// 34.550 us; speedup vs baseline: 24.8784x; 24.8784x over previous
//
#include <hip/hip_runtime.h>

// Lovasz-Softmax without sorting (exact up to bin-midpoint error <= 0.5/NB):
//  - ties in the error value don't change the loss (telescoping within
//    equal-error groups)
//  - jaccard is monotone along the sorted order with total variation 1, so
//    binning errors and using midpoints has per-class error <= 0.5/NB.
// R2: LDS-privatized histograms (R1's global atomics caused 374MB of HBM
// write traffic and 821us of same-address serialization).

constexpr int NCLS = 6;
constexpr int HW   = 512 * 512;
constexpr int NPIX = 8 * HW;
constexpr int NB   = 1024;       // bin width 1/1024 -> loss error <= 4.9e-4
constexpr int NROWS = 2 * NCLS;  // rows 0..5: non-fg (p_c, c!=lab); 6..11: fg (1-p_lab)
constexpr int HIST_WORDS = NROWS * NB;

constexpr int HBLK = 256;        // blocks for hist kernel
constexpr int HTHR = 1024;       // threads per block

__global__ __launch_bounds__(HTHR) void lovasz_hist(
    const float* __restrict__ logits, const int* __restrict__ labels,
    unsigned* __restrict__ ghist) {
  __shared__ unsigned lh[HIST_WORDS];        // 48 KB
  for (int i = threadIdx.x; i < HIST_WORDS; i += HTHR) lh[i] = 0u;
  __syncthreads();

  const int nquads = NPIX / 4;
  for (int q = blockIdx.x * HTHR + threadIdx.x; q < nquads; q += HBLK * HTHR) {
    int n4 = q << 2;
    int b  = n4 >> 18;                       // / HW
    int hw = n4 & (HW - 1);

    int4 lab4 = *reinterpret_cast<const int4*>(labels + n4);
    int labs[4] = {lab4.x, lab4.y, lab4.z, lab4.w};
    if ((lab4.x | lab4.y | lab4.z | lab4.w) == 0) continue;  // all ignored

    float xx[NCLS][4];
    size_t base = ((size_t)b * NCLS) << 18;
#pragma unroll
    for (int c = 0; c < NCLS; ++c) {
      float4 v = *reinterpret_cast<const float4*>(logits + base + ((size_t)c << 18) + hw);
      xx[c][0] = v.x; xx[c][1] = v.y; xx[c][2] = v.z; xx[c][3] = v.w;
    }

#pragma unroll
    for (int j = 0; j < 4; ++j) {
      int lab = labs[j];
      if (lab == 0) continue;                // IGNORE: contributes exactly 0
      float m = xx[0][j];
#pragma unroll
      for (int c = 1; c < NCLS; ++c) m = fmaxf(m, xx[c][j]);
      float e[NCLS];
      float s = 0.f;
#pragma unroll
      for (int c = 0; c < NCLS; ++c) { e[c] = __expf(xx[c][j] - m); s += e[c]; }
      float inv = 1.0f / s;
#pragma unroll
      for (int c = 0; c < NCLS; ++c) {
        float p   = e[c] * inv;
        bool  fg  = (c == lab);
        float err = fg ? 1.0f - p : p;
        int bin = (int)(err * (float)NB);
        bin = bin < 0 ? 0 : (bin > NB - 1 ? NB - 1 : bin);
        int row = fg ? NCLS + c : c;
        atomicAdd(&lh[row * NB + bin], 1u);
      }
    }
  }

  __syncthreads();
  for (int i = threadIdx.x; i < HIST_WORDS; i += HTHR) {
    unsigned v = lh[i];
    if (v) atomicAdd(&ghist[i], v);
  }
}

// One block per class: descending-bin scan computing
//   sum over bins: e_mid * (jac(n+dn, f+df) - jac(n, f))
// jac(n,f) = 1 - (g - f)/(g + n - f); for present classes union >= g > 0.
__global__ __launch_bounds__(256) void lovasz_scan(
    const unsigned* __restrict__ ghist, float* __restrict__ res) {
  const int c = blockIdx.x;
  const unsigned* ha = ghist + c * NB;           // non-fg contributions
  const unsigned* hf = ghist + (NCLS + c) * NB;  // fg contributions
  const int t = threadIdx.x;                     // 256 threads
  const int K = NB / 256;                        // bins per thread
  const int hi = NB - 1 - t * K;                 // chunk: hi, hi-1, ...

  unsigned dn = 0, df = 0;
  for (int i = 0; i < K; ++i) { dn += ha[hi - i] + hf[hi - i]; df += hf[hi - i]; }

  __shared__ unsigned sn[256], sf[256];
  sn[t] = dn; sf[t] = df;
  __syncthreads();
  for (int off = 1; off < 256; off <<= 1) {      // Hillis-Steele inclusive scan
    unsigned an = (t >= off) ? sn[t - off] : 0u;
    unsigned af = (t >= off) ? sf[t - off] : 0u;
    __syncthreads();
    sn[t] += an; sf[t] += af;
    __syncthreads();
  }
  const unsigned total_f = sf[255];              // gts
  const unsigned n0 = sn[t] - dn;                // exclusive prefix
  const unsigned f0 = sf[t] - df;

  double contrib = 0.0;
  if (total_f > 0) {
    const double gts = (double)total_f;
    unsigned n = n0, f = f0;
    for (int i = 0; i < K; ++i) {
      int bidx = hi - i;
      unsigned dnb = ha[bidx] + hf[bidx];
      if (!dnb) continue;
      unsigned dfb = hf[bidx];
      double ub = gts + (double)n - (double)f;
      double jb = 1.0 - (gts - (double)f) / ub;
      n += dnb; f += dfb;
      double ua = gts + (double)n - (double)f;
      double ja = 1.0 - (gts - (double)f) / ua;
      double e  = ((double)bidx + 0.5) * (1.0 / (double)NB);
      contrib += e * (ja - jb);
    }
  }

  __shared__ double sd[256];
  sd[t] = contrib;
  __syncthreads();
  for (int off = 128; off > 0; off >>= 1) {
    if (t < off) sd[t] += sd[t + off];
    __syncthreads();
  }
  if (t == 0) {
    res[c]        = (total_f > 0) ? (float)sd[0] : 0.0f;
    res[NCLS + c] = (total_f > 0) ? 1.0f : 0.0f;
  }
}

__global__ void lovasz_final(const float* __restrict__ res, float* __restrict__ out) {
  float s = 0.f, np = 0.f;
  for (int c = 0; c < NCLS; ++c) { s += res[c]; np += res[NCLS + c]; }
  out[0] = s / fmaxf(np, 1.0f);
}

extern "C" void kernel_launch(void* const* d_in, const int* in_sizes, int n_in,
                              void* d_out, int out_size, void* d_ws, size_t ws_size,
                              hipStream_t stream) {
  const float* logits = (const float*)d_in[0];
  const int*   labels = (const int*)d_in[1];

  unsigned* ghist = (unsigned*)d_ws;
  float*    res   = (float*)(ghist + HIST_WORDS);

  size_t clear_bytes = (size_t)HIST_WORDS * sizeof(unsigned) + 2ull * NCLS * sizeof(float);
  hipMemsetAsync(d_ws, 0, clear_bytes, stream);

  lovasz_hist<<<HBLK, HTHR, 0, stream>>>(logits, labels, ghist);
  lovasz_scan<<<NCLS, 256, 0, stream>>>(ghist, res);
  lovasz_final<<<1, 1, 0, stream>>>(res, (float*)d_out);
}

// Round 3
// 34.505 us; speedup vs baseline: 24.9104x; 1.0013x over previous
//
#include <hip/hip_runtime.h>

// Lovasz-Softmax without sorting (exact up to bin-midpoint error <= 0.5/NB):
//  - ties in the error value don't change the loss (telescoping within
//    equal-error groups)
//  - jaccard is monotone along the sorted order with total variation 1, so
//    binning errors and using midpoints has per-class error <= 4.9e-4 (NB=1024).
// R3: replace rocclr fillBuffer (measured 39us for 48KB!) with own zero
// kernel; fuse scan+final into one single-block 6-wave kernel (shfl scans,
// no block barriers in the scan itself). 3 dispatches total.

constexpr int NCLS = 6;
constexpr int HW   = 512 * 512;
constexpr int NPIX = 8 * HW;
constexpr int NB   = 1024;       // bin width 1/1024 -> loss error <= 4.9e-4
constexpr int NROWS = 2 * NCLS;  // rows 0..5: non-fg (p_c, c!=lab); 6..11: fg (1-p_lab)
constexpr int HIST_WORDS = NROWS * NB;   // 12288 u32 = 48 KB

constexpr int HBLK = 256;        // blocks for hist kernel
constexpr int HTHR = 1024;       // threads per block

__global__ __launch_bounds__(1024) void lovasz_zero(unsigned* __restrict__ g) {
  int i = blockIdx.x * 1024 + threadIdx.x;
  if (i < HIST_WORDS) g[i] = 0u;
}

__global__ __launch_bounds__(HTHR) void lovasz_hist(
    const float* __restrict__ logits, const int* __restrict__ labels,
    unsigned* __restrict__ ghist) {
  __shared__ unsigned lh[HIST_WORDS];        // 48 KB
  for (int i = threadIdx.x; i < HIST_WORDS; i += HTHR) lh[i] = 0u;
  __syncthreads();

  const int nquads = NPIX / 4;
  for (int q = blockIdx.x * HTHR + threadIdx.x; q < nquads; q += HBLK * HTHR) {
    int n4 = q << 2;
    int b  = n4 >> 18;                       // / HW
    int hw = n4 & (HW - 1);

    int4 lab4 = *reinterpret_cast<const int4*>(labels + n4);
    int labs[4] = {lab4.x, lab4.y, lab4.z, lab4.w};
    if ((lab4.x | lab4.y | lab4.z | lab4.w) == 0) continue;  // all ignored

    float xx[NCLS][4];
    size_t base = ((size_t)b * NCLS) << 18;
#pragma unroll
    for (int c = 0; c < NCLS; ++c) {
      float4 v = *reinterpret_cast<const float4*>(logits + base + ((size_t)c << 18) + hw);
      xx[c][0] = v.x; xx[c][1] = v.y; xx[c][2] = v.z; xx[c][3] = v.w;
    }

#pragma unroll
    for (int j = 0; j < 4; ++j) {
      int lab = labs[j];
      if (lab == 0) continue;                // IGNORE: contributes exactly 0
      float m = xx[0][j];
#pragma unroll
      for (int c = 1; c < NCLS; ++c) m = fmaxf(m, xx[c][j]);
      float e[NCLS];
      float s = 0.f;
#pragma unroll
      for (int c = 0; c < NCLS; ++c) { e[c] = __expf(xx[c][j] - m); s += e[c]; }
      float inv = 1.0f / s;
#pragma unroll
      for (int c = 0; c < NCLS; ++c) {
        float p   = e[c] * inv;
        bool  fg  = (c == lab);
        float err = fg ? 1.0f - p : p;
        int bin = (int)(err * (float)NB);
        bin = bin < 0 ? 0 : (bin > NB - 1 ? NB - 1 : bin);
        int row = fg ? NCLS + c : c;
        atomicAdd(&lh[row * NB + bin], 1u);
      }
    }
  }

  __syncthreads();
  for (int i = threadIdx.x; i < HIST_WORDS; i += HTHR) {
    unsigned v = lh[i];
    if (v) atomicAdd(&ghist[i], v);
  }
}

// One block, 6 waves: wave w handles class w. Each lane owns 16 contiguous
// bins; lane 0 has the highest-error bins so lane order == descending order.
// Wave-inclusive shfl scan gives each lane its exclusive (n, f) prefix; then
// a per-lane descending walk accumulates e_mid * (jac_after - jac_before).
__global__ __launch_bounds__(64 * NCLS) void lovasz_scanfinal(
    const unsigned* __restrict__ ghist, float* __restrict__ out) {
  const int wave = threadIdx.x >> 6;       // class index
  const int lane = threadIdx.x & 63;
  const unsigned* ha = ghist + wave * NB;
  const unsigned* hf = ghist + (NCLS + wave) * NB;

  const int base = NB - 16 - lane * 16;    // lane 0 -> bins 1008..1023
  unsigned a[16], f[16];
#pragma unroll
  for (int i = 0; i < 16; ++i) { a[i] = ha[base + i]; f[i] = hf[base + i]; }

  unsigned dn = 0, df = 0;
#pragma unroll
  for (int i = 0; i < 16; ++i) { dn += a[i] + f[i]; df += f[i]; }

  unsigned sn = dn, sf = df;               // inclusive wave scan
  for (int off = 1; off < 64; off <<= 1) {
    unsigned tn = __shfl_up(sn, off);
    unsigned tf = __shfl_up(sf, off);
    if (lane >= off) { sn += tn; sf += tf; }
  }
  const unsigned total_f = __shfl(sf, 63); // gts
  unsigned n  = sn - dn;                   // exclusive prefix (larger errors)
  unsigned ff = sf - df;

  double contrib = 0.0;
  if (total_f > 0) {
    const double gts = (double)total_f;
    for (int i = 15; i >= 0; --i) {        // descending bins within chunk
      unsigned dnb = a[i] + f[i];
      if (!dnb) continue;
      unsigned dfb = f[i];
      double ub = gts + (double)n - (double)ff;
      double jb = 1.0 - (gts - (double)ff) / ub;
      n += dnb; ff += dfb;
      double ua = gts + (double)n - (double)ff;
      double ja = 1.0 - (gts - (double)ff) / ua;
      double e  = ((double)(base + i) + 0.5) * (1.0 / (double)NB);
      contrib += e * (ja - jb);
    }
  }
  for (int off = 32; off > 0; off >>= 1) contrib += __shfl_down(contrib, off);

  __shared__ double   sloss[NCLS];
  __shared__ unsigned spres[NCLS];
  if (lane == 0) { sloss[wave] = contrib; spres[wave] = total_f; }
  __syncthreads();
  if (threadIdx.x == 0) {
    double s = 0.0, np = 0.0;
    for (int k = 0; k < NCLS; ++k)
      if (spres[k] > 0) { s += sloss[k]; np += 1.0; }
    out[0] = (float)(s / (np > 0.0 ? np : 1.0));
  }
}

extern "C" void kernel_launch(void* const* d_in, const int* in_sizes, int n_in,
                              void* d_out, int out_size, void* d_ws, size_t ws_size,
                              hipStream_t stream) {
  const float* logits = (const float*)d_in[0];
  const int*   labels = (const int*)d_in[1];
  unsigned*    ghist  = (unsigned*)d_ws;

  lovasz_zero<<<(HIST_WORDS + 1023) / 1024, 1024, 0, stream>>>(ghist);
  lovasz_hist<<<HBLK, HTHR, 0, stream>>>(logits, labels, ghist);
  lovasz_scanfinal<<<1, 64 * NCLS, 0, stream>>>(ghist, (float*)d_out);
}